// Round 1
// baseline (183.189 us; speedup 1.0000x reference)
//
#include <hip/hip_runtime.h>

// Problem constants (from reference): B=16384, D=255, K=4, L=16, T=1020
constexpr int T_TUN = 1020;
constexpr int D_DST = 255;
constexpr int L_LNK = 16;
constexpr float EPS = 1e-8f;
constexpr int ROWS_PER_BLOCK = 8;   // 4 waves x 2 rows
constexpr int ROWS_PER_WAVE  = 2;
constexpr int REP_STRIDE = 20;      // 16 links + pad for bank spread

__global__ __launch_bounds__(256) void rowloss_kernel(
    const float* __restrict__ pred,     // [B, T]
    const float* __restrict__ demands,  // [B, D]
    const float* __restrict__ cur,      // [B, L]
    const float* __restrict__ caps,     // [L]
    const int*   __restrict__ t2l,      // [T]
    float* __restrict__ partials)       // [gridDim.x]
{
  const int tid  = threadIdx.x;
  const int lane = tid & 63;
  const int w    = tid >> 6;   // wave id 0..3

  // per-wave replicated bins: 8 replicas x 20 (16 used) floats
  __shared__ float bins_all[4][8 * REP_STRIDE];
  __shared__ float wacc[4];
  float* bins = bins_all[w];

  const int mylink = lane & 15;
  const float capinv = 1.0f / (caps[mylink] + EPS);

  // Preload link ids for this lane's dsts d = lane + 64*j (row-invariant).
  // Store as bin offsets including replica base.
  const int repbase = (lane >> 3) * REP_STRIDE;
  int boff[4][4];
  bool dvalid[4];
#pragma unroll
  for (int j = 0; j < 4; ++j) {
    const int d = lane + 64 * j;
    dvalid[j] = (d < D_DST);
    const int dd = dvalid[j] ? d : 0;
    const int4 lk = ((const int4*)t2l)[dd];   // t2l[4d..4d+3], 16B aligned
    boff[j][0] = repbase + lk.x;
    boff[j][1] = repbase + lk.y;
    boff[j][2] = repbase + lk.z;
    boff[j][3] = repbase + lk.w;
  }

  float acc = 0.0f;
  const int row0 = blockIdx.x * ROWS_PER_BLOCK + w * ROWS_PER_WAVE;

  for (int r = 0; r < ROWS_PER_WAVE; ++r) {
    const int b = row0 + r;

    // zero bins (160 floats); DS ops are in-order within a wave
    bins[lane] = 0.0f;
    bins[lane + 64] = 0.0f;
    if (lane < 32) bins[lane + 128] = 0.0f;

    const float  mycur = cur[(size_t)b * L_LNK + mylink];
    const float4* prow = (const float4*)(pred + (size_t)b * T_TUN);
    const float*  drow = demands + (size_t)b * D_DST;

#pragma unroll
    for (int j = 0; j < 4; ++j) {
      if (!dvalid[j]) continue;           // only lane63/j3 diverges
      const int d = lane + 64 * j;
      const float4 r4 = prow[d];          // ratios for tunnels 4d..4d+3
      const float dem = drow[d];          // shared demand for the 4 tunnels
      atomicAdd(&bins[boff[j][0]], r4.x * dem);
      atomicAdd(&bins[boff[j][1]], r4.y * dem);
      atomicAdd(&bins[boff[j][2]], r4.z * dem);
      atomicAdd(&bins[boff[j][3]], r4.w * dem);
    }

    // merge 8 replicas -> replica 0 (tree; wave-internal, DS in-order)
    {
      const int rr = lane >> 4;          // 0..3
      const int c  = lane & 15;
      bins[rr * REP_STRIDE + c] += bins[(rr + 4) * REP_STRIDE + c];
    }
    if (lane < 32) {
      const int rr = lane >> 4;          // 0..1
      const int c  = lane & 15;
      bins[rr * REP_STRIDE + c] += bins[(rr + 2) * REP_STRIDE + c];
    }
    if (lane < 16) {
      bins[lane] += bins[REP_STRIDE + lane];
    }

    // every lane reads a valid final sum (bins[0..15])
    const float u = bins[mylink] * capinv;
    float s1 = u, s2 = u * u, s3 = u * mycur, mx = u;
#pragma unroll
    for (int m = 1; m < 16; m <<= 1) {
      s1 += __shfl_xor(s1, m, 64);
      s2 += __shfl_xor(s2, m, 64);
      s3 += __shfl_xor(s3, m, 64);
      const float o = __shfl_xor(mx, m, 64);
      mx = fmaxf(mx, o);
    }
    const float mean = s1 * (1.0f / 16.0f);
    const float var  = (s2 - 16.0f * mean * mean) * (1.0f / 15.0f);  // ddof=1
    acc += 0.3f * var + 0.5f * s3 + 0.2f * mx;
  }

  if (lane == 0) wacc[w] = acc;
  __syncthreads();
  if (tid == 0) partials[blockIdx.x] = wacc[0] + wacc[1] + wacc[2] + wacc[3];
}

__global__ __launch_bounds__(256) void reduce_kernel(
    const float* __restrict__ partials, int n, float* __restrict__ out, float invB)
{
  __shared__ float s[256];
  const int tid = threadIdx.x;
  float a = 0.0f;
  for (int i = tid; i < n; i += 256) a += partials[i];
  s[tid] = a;
  __syncthreads();
  for (int st = 128; st > 0; st >>= 1) {
    if (tid < st) s[tid] += s[tid + st];
    __syncthreads();
  }
  if (tid == 0) out[0] = s[0] * invB;
}

extern "C" void kernel_launch(void* const* d_in, const int* in_sizes, int n_in,
                              void* d_out, int out_size, void* d_ws, size_t ws_size,
                              hipStream_t stream) {
  const float* pred    = (const float*)d_in[0];  // [B, T]
  const float* demands = (const float*)d_in[1];  // [B, D]
  const float* cur     = (const float*)d_in[2];  // [B, L]
  const float* caps    = (const float*)d_in[3];  // [L]
  const int*   t2l     = (const int*)d_in[4];    // [T]
  float* out = (float*)d_out;

  const int L = in_sizes[3];          // 16
  const int B = in_sizes[2] / L;      // 16384

  const int grid = B / ROWS_PER_BLOCK;  // 2048
  float* partials = (float*)d_ws;       // grid floats

  rowloss_kernel<<<grid, 256, 0, stream>>>(pred, demands, cur, caps, t2l, partials);
  reduce_kernel<<<1, 256, 0, stream>>>(partials, grid, out, 1.0f / (float)B);
}

// Round 3
// 111.320 us; speedup vs baseline: 1.6456x; 1.6456x over previous
//
#include <hip/hip_runtime.h>

// Problem constants (from reference): B=16384, D=255, K=4, L=16, T=1020
constexpr int T_TUN = 1020;
constexpr int D_DST = 255;
constexpr int L_LNK = 16;
constexpr float EPS = 1e-8f;
constexpr int ROWS_PER_BLOCK = 8;   // 4 waves x 2 rows
constexpr int ROWS_PER_WAVE  = 2;
constexpr int PSTRIDE = 16;         // per-lane private bin region (floats)

__global__ __launch_bounds__(256) void rowloss_kernel(
    const float* __restrict__ pred,     // [B, T]
    const float* __restrict__ demands,  // [B, D]
    const float* __restrict__ cur,      // [B, L]
    const float* __restrict__ caps,     // [L]
    const int*   __restrict__ t2l,      // [T]
    float* __restrict__ partials)       // [gridDim.x]
{
  const int tid  = threadIdx.x;
  const int lane = tid & 63;
  const int w    = tid >> 6;   // wave id 0..3

  // per-lane private histograms: no atomics, no contention.
  // addr(lane', bin) = lane'*16 + bin
  // column reduce: lane (g=lane>>4, b=lane&15) sums lane' = 4k+g, k=0..15
  //   -> addr = (4k+g)*16 + b = lane + 64*k   (max 1023, in-bounds)
  __shared__ float priv_all[4][64 * PSTRIDE];
  __shared__ float wacc[4];
  float* priv = priv_all[w];
  float* mine = priv + lane * PSTRIDE;

  const int b16 = lane & 15;
  const float capinv = 1.0f / (caps[b16] + EPS);

  // Row-invariant scatter offsets (bins for this lane's 4 dsts x 4 tunnels)
  int off[4][4];
  bool dv[4];
#pragma unroll
  for (int j = 0; j < 4; ++j) {
    const int d = lane + 64 * j;
    dv[j] = (d < D_DST);
    const int dd = dv[j] ? d : 0;
    const int4 lk = ((const int4*)t2l)[dd];   // t2l[4d..4d+3]
    off[j][0] = lane * PSTRIDE + lk.x;
    off[j][1] = lane * PSTRIDE + lk.y;
    off[j][2] = lane * PSTRIDE + lk.z;
    off[j][3] = lane * PSTRIDE + lk.w;
  }

  float acc = 0.0f;
  const int row0 = blockIdx.x * ROWS_PER_BLOCK + w * ROWS_PER_WAVE;

#pragma unroll
  for (int r = 0; r < ROWS_PER_WAVE; ++r) {
    const int b = row0 + r;

    __builtin_amdgcn_wave_barrier();  // keep zero-writes after prior row's reads

    // zero my 16 bins (4x ds_write_b128, 64B-aligned base)
    const float4 z = make_float4(0.f, 0.f, 0.f, 0.f);
    float4* mz = (float4*)mine;
    mz[0] = z; mz[1] = z; mz[2] = z; mz[3] = z;

    const float  mycur = cur[(size_t)b * L_LNK + b16];
    const float4* prow = (const float4*)(pred + (size_t)b * T_TUN);
    const float*  drow = demands + (size_t)b * D_DST;

    // scatter: plain RMW into private bins (DS pipe is in-order per wave)
#pragma unroll
    for (int j = 0; j < 4; ++j) {
      if (!dv[j]) continue;            // only lane63/j3 diverges
      const int d = lane + 64 * j;
      const float4 r4 = prow[d];       // ratios for tunnels 4d..4d+3
      const float dem = drow[d];       // demand shared by the 4 tunnels
      priv[off[j][0]] += r4.x * dem;
      priv[off[j][1]] += r4.y * dem;
      priv[off[j][2]] += r4.z * dem;
      priv[off[j][3]] += r4.w * dem;
    }

    __builtin_amdgcn_wave_barrier();  // keep reduce reads after scatter writes

    // column reduce: 16 independent ds_reads, 2-way bank aliasing only.
    float cs = 0.0f;
#pragma unroll
    for (int k = 0; k < 16; ++k) cs += priv[lane + 64 * k];
    // fold the 4 lane-groups (g = bits 4..5 of lane) -> full bins[lane&15]
    cs += __shfl_xor(cs, 16, 64);
    cs += __shfl_xor(cs, 32, 64);

    const float u = cs * capinv;
    float s1 = u, s2 = u * u, s3 = u * mycur, mx = u;
#pragma unroll
    for (int m = 1; m < 16; m <<= 1) {
      s1 += __shfl_xor(s1, m, 64);
      s2 += __shfl_xor(s2, m, 64);
      s3 += __shfl_xor(s3, m, 64);
      const float o = __shfl_xor(mx, m, 64);
      mx = fmaxf(mx, o);
    }
    const float mean = s1 * (1.0f / 16.0f);
    const float var  = (s2 - 16.0f * mean * mean) * (1.0f / 15.0f);  // ddof=1
    acc += 0.3f * var + 0.5f * s3 + 0.2f * mx;
  }

  if (lane == 0) wacc[w] = acc;
  __syncthreads();
  if (tid == 0) partials[blockIdx.x] = wacc[0] + wacc[1] + wacc[2] + wacc[3];
}

__global__ __launch_bounds__(256) void reduce_kernel(
    const float* __restrict__ partials, int n, float* __restrict__ out, float invB)
{
  __shared__ float s[256];
  const int tid = threadIdx.x;
  float a = 0.0f;
  for (int i = tid; i < n; i += 256) a += partials[i];
  s[tid] = a;
  __syncthreads();
  for (int st = 128; st > 0; st >>= 1) {
    if (tid < st) s[tid] += s[tid + st];
    __syncthreads();
  }
  if (tid == 0) out[0] = s[0] * invB;
}

extern "C" void kernel_launch(void* const* d_in, const int* in_sizes, int n_in,
                              void* d_out, int out_size, void* d_ws, size_t ws_size,
                              hipStream_t stream) {
  const float* pred    = (const float*)d_in[0];  // [B, T]
  const float* demands = (const float*)d_in[1];  // [B, D]
  const float* cur     = (const float*)d_in[2];  // [B, L]
  const float* caps    = (const float*)d_in[3];  // [L]
  const int*   t2l     = (const int*)d_in[4];    // [T]
  float* out = (float*)d_out;

  const int L = in_sizes[3];          // 16
  const int B = in_sizes[2] / L;      // 16384

  const int grid = B / ROWS_PER_BLOCK;  // 2048
  float* partials = (float*)d_ws;       // grid floats

  rowloss_kernel<<<grid, 256, 0, stream>>>(pred, demands, cur, caps, t2l, partials);
  reduce_kernel<<<1, 256, 0, stream>>>(partials, grid, out, 1.0f / (float)B);
}